// Round 6
// baseline (688.116 us; speedup 1.0000x reference)
//
#include <hip/hip_runtime.h>
#include <hip/hip_bf16.h>

#define HDIM 1024
#define SEQ  2048
#define BATCH 32
#define M_TOTAL (BATCH * SEQ)   // 65536
#define BM 256
#define BN 256
#define BK 32
#define KSTEPS (HDIM / BK)      // 32
#define NSLICE 16               // 4 n-blocks x 4 n-waves

typedef __bf16 bf16x8 __attribute__((ext_vector_type(8)));
typedef float  f32x4  __attribute__((ext_vector_type(4)));
typedef unsigned short u16;
#define AS1 __attribute__((address_space(1)))
#define AS3 __attribute__((address_space(3)))

__device__ __forceinline__ u16 f2bf(float f) {
    unsigned int u = __float_as_uint(f);
    u += 0x7FFFu + ((u >> 16) & 1u);   // round-to-nearest-even
    return (u16)(u >> 16);
}

// ---- fp32 -> bf16, 8 elems/thread, grid-stride (2048 blocks, not 32768:
// tiny-block dispatch rate was a suspect in the invisible 425 us pool) ----
__global__ __launch_bounds__(256) void cvt_kernel(const float* __restrict__ in,
                                                  u16* __restrict__ out, int n8) {
    const int stride = gridDim.x * 256;
    for (int idx = blockIdx.x * 256 + threadIdx.x; idx < n8; idx += stride) {
        size_t i = (size_t)idx * 8;
        float4 f0 = *(const float4*)(in + i);
        float4 f1 = *(const float4*)(in + i + 4);
        uint4 v;
        v.x = (unsigned)f2bf(f0.x) | ((unsigned)f2bf(f0.y) << 16);
        v.y = (unsigned)f2bf(f0.z) | ((unsigned)f2bf(f0.w) << 16);
        v.z = (unsigned)f2bf(f1.x) | ((unsigned)f2bf(f1.y) << 16);
        v.w = (unsigned)f2bf(f1.z) | ((unsigned)f2bf(f1.w) << 16);
        *(uint4*)(out + i) = v;
    }
}

// ---- qb[b][o] = query[b]·Wa_w[o] + Wa_b[o] + Ua_b[o] (fp32) ----
__global__ __launch_bounds__(256) void qb_kernel(const float* __restrict__ query,
                                                 const float* __restrict__ Wa_w,
                                                 const float* __restrict__ Wa_b,
                                                 const float* __restrict__ Ua_b,
                                                 float* __restrict__ qb) {
    __shared__ float qs[HDIM];
    const int b = blockIdx.x;
    const int tid = threadIdx.x;
    ((float4*)qs)[tid] = ((const float4*)(query + b * HDIM))[tid];
    __syncthreads();
    const int lane = tid & 63;
    const int w = tid >> 6;
    const int obase = blockIdx.y * 64 + w * 16;
    for (int i = 0; i < 16; i++) {
        int o = obase + i;
        const float4* wrow = (const float4*)(Wa_w + (size_t)o * HDIM);
        float s = 0.f;
        #pragma unroll
        for (int j = 0; j < 4; j++) {
            float4 wv = wrow[j * 64 + lane];
            float4 qv = ((const float4*)qs)[j * 64 + lane];
            s += wv.x * qv.x + wv.y * qv.y + wv.z * qv.z + wv.w * qv.w;
        }
        #pragma unroll
        for (int m = 1; m < 64; m <<= 1) s += __shfl_xor(s, m);
        if (lane == 0) qb[b * HDIM + o] = s + Wa_b[o] + Ua_b[o];
    }
}

// raw ds_read_b128 (invisible to LDS-DMA alias waitcnt logic); lgkm waits are
// manual COUNTED waits (rule #18: wait + sched_barrier(0) before MFMA).
#define DSREAD(dst, base, imm) \
    asm volatile("ds_read_b128 %0, %1 offset:" #imm : "=v"(dst) : "v"(base))

#define MFMA4(mi, av, c0, c1, c2, c3) \
    acc[mi][0] = __builtin_amdgcn_mfma_f32_16x16x32_bf16(av, c0, acc[mi][0], 0, 0, 0); \
    acc[mi][1] = __builtin_amdgcn_mfma_f32_16x16x32_bf16(av, c1, acc[mi][1], 0, 0, 0); \
    acc[mi][2] = __builtin_amdgcn_mfma_f32_16x16x32_bf16(av, c2, acc[mi][2], 0, 0, 0); \
    acc[mi][3] = __builtin_amdgcn_mfma_f32_16x16x32_bf16(av, c3, acc[mi][3], 0, 0, 0);

// ---- GEMM keysb·Ua^T + fused tanh + Va dot -> deterministic score slices ----
// 256x256 tile, BK=32, 8 waves (2M x 4N). A through a 4-slot LDS ring (64 KiB);
// B DIRECT FROM GLOBAL (uab = 2 MiB, L2-resident): 4 dwordx4/wave/tile into
// registers, prefetched one tile ahead (ping-pong). Cuts LDS reads 96->64 and
// gl_lds 4->2 per wave per tile. Round-4 counted-lgkm pipelined skeleton.
// vm ledger/tile (issue order): glA(t+3) x2, b(t+1) x4 -> steady gate vmcnt(6).
__global__ __launch_bounds__(512, 2) void gemm_score_kernel(const u16* __restrict__ keysb,
                                                            const u16* __restrict__ uab,
                                                            const float* __restrict__ qb,
                                                            const float* __restrict__ vaw,
                                                            float* __restrict__ sp) {
    __shared__ __align__(16) u16 As[4][BM * BK];   // 4 x 16 KB = 64 KiB

    const int tid  = threadIdx.x;
    const int lane = tid & 63;
    const int w    = tid >> 6;          // 0..7
    const int wm   = w >> 2;            // 0..1  -> rows [wm*128, +128)
    const int wn   = w & 3;             // 0..3  -> cols [wn*64, +64)

    // XCD-chunked swizzle: 128 consecutive remapped blocks per XCD, n-fastest
    const int bid = blockIdx.y * 4 + blockIdx.x;         // dispatch order
    const int swz = (bid & 7) * 128 + (bid >> 3);        // bijective (1024 % 8 == 0)
    const int bx  = swz & 3;
    const int by  = swz >> 2;
    const int n0  = bx * BN;
    const int m0  = by * BM;

    // ---- A staging (linear LDS dest, pre-swizzled global source) ----
    // row = 64 B = 4 x 16B slots; LDS(r, s) holds global slot s ^ ((r>>1)&3)
    const int srow = lane >> 2;                          // row within 16-row chunk
    const int cs   = (lane & 3) ^ ((lane >> 3) & 3);     // swizzled source slot
    const u16* gA0 = keysb + (size_t)(m0 + w * 32 + srow) * HDIM + cs * 8;
    const int ldst = w * 32 * BK;                        // wave's 32-row group

    // ---- fragment addressing ----
    const int fr = lane & 15;
    const int fq = lane >> 4;
    const int sA = fq ^ ((fr >> 1) & 3);                 // row-bit-independent
    const unsigned aB0 = (unsigned)(unsigned long long)(const AS3 u16*)&As[0][0]
                       + (unsigned)(((wm * 128 + fr) * BK + sA * 8) * 2);
    // B fragment global bases (AS1 so loads emit global_load: vmcnt-only)
    const AS1 u16* gBp0 = (const AS1 u16*)uab
                        + ((size_t)(n0 + wn * 64 + fr) * HDIM + fq * 8);
    const AS1 u16* gBp1 = gBp0 + (size_t)16 * HDIM;
    const AS1 u16* gBp2 = gBp0 + (size_t)32 * HDIM;
    const AS1 u16* gBp3 = gBp0 + (size_t)48 * HDIM;

    f32x4 acc[8][4] = {};

#define STAGE_A(kt) { \
    u16* d = &As[(kt) & 3][ldst]; \
    __builtin_amdgcn_global_load_lds((AS1 void*)(gA0 + (size_t)(kt) * BK), (AS3 void*)d, 16, 0, 0); \
    __builtin_amdgcn_global_load_lds((AS1 void*)(gA0 + (size_t)(kt) * BK + 16 * HDIM), (AS3 void*)(d + 16 * BK), 16, 0, 0); }

    bf16x8 a0, a1, a2, a3, a4, a5, a6, a7;
    bf16x8 bA0, bA1, bA2, bA3, bB0, bB1, bB2, bB3;

    // prologue: b(0) first (oldest in ledger), then A slots 0..2 staged
    bA0 = *(const AS1 bf16x8*)(gBp0);
    bA1 = *(const AS1 bf16x8*)(gBp1);
    bA2 = *(const AS1 bf16x8*)(gBp2);
    bA3 = *(const AS1 bf16x8*)(gBp3);
    STAGE_A(0) STAGE_A(1) STAGE_A(2)
    asm volatile("s_waitcnt vmcnt(4)" ::: "memory");   // b(0)+glA(0) done
    __builtin_amdgcn_s_barrier();
    DSREAD(a0, aB0, 0);    DSREAD(a1, aB0, 1024);
    DSREAD(a2, aB0, 2048); DSREAD(a3, aB0, 3072);

#define GTILE(t, c0, c1, c2, c3, d0, d1, d2, d3) { \
    const unsigned at = aB0 + (((t) & 3) << 14);         /* slot stride 16 KiB */ \
    /* P0: stage A(t+3), reads a4-7(t), prefetch b(t+1), MFMA mi0-3 */ \
    if ((t) + 3 < KSTEPS) STAGE_A((t) + 3) \
    DSREAD(a4, at, 4096); DSREAD(a5, at, 5120); \
    DSREAD(a6, at, 6144); DSREAD(a7, at, 7168); \
    if ((t) + 1 < KSTEPS) { \
        const size_t toff = (size_t)((t) + 1) * BK; \
        d0 = *(const AS1 bf16x8*)(gBp0 + toff); \
        d1 = *(const AS1 bf16x8*)(gBp1 + toff); \
        d2 = *(const AS1 bf16x8*)(gBp2 + toff); \
        d3 = *(const AS1 bf16x8*)(gBp3 + toff); \
    } \
    asm volatile("s_waitcnt lgkmcnt(4)" ::: "memory");   /* a0-3(t) done */ \
    __builtin_amdgcn_sched_barrier(0); \
    __builtin_amdgcn_s_setprio(1); \
    MFMA4(0, a0, c0, c1, c2, c3) \
    MFMA4(1, a1, c0, c1, c2, c3) \
    MFMA4(2, a2, c0, c1, c2, c3) \
    MFMA4(3, a3, c0, c1, c2, c3) \
    __builtin_amdgcn_s_setprio(0); \
    /* P1: prefetch a0-3(t+1), MFMA mi4-7 */ \
    if ((t) + 1 < KSTEPS) { \
        const unsigned an = aB0 + ((((t) + 1) & 3) << 14); \
        DSREAD(a0, an, 0);    DSREAD(a1, an, 1024); \
        DSREAD(a2, an, 2048); DSREAD(a3, an, 3072); \
        asm volatile("s_waitcnt lgkmcnt(4)" ::: "memory");   /* a4-7(t) done */ \
    } else { \
        asm volatile("s_waitcnt lgkmcnt(0)" ::: "memory"); \
    } \
    __builtin_amdgcn_sched_barrier(0); \
    __builtin_amdgcn_s_setprio(1); \
    MFMA4(4, a4, c0, c1, c2, c3) \
    MFMA4(5, a5, c0, c1, c2, c3) \
    MFMA4(6, a6, c0, c1, c2, c3) \
    MFMA4(7, a7, c0, c1, c2, c3) \
    __builtin_amdgcn_s_setprio(0); \
    /* ring gate: slot t+2 retired for P1(t+1)'s reads; keep 6 in flight */ \
    if ((t) < KSTEPS - 3)       asm volatile("s_waitcnt vmcnt(6)" ::: "memory"); \
    else if ((t) == KSTEPS - 3) asm volatile("s_waitcnt vmcnt(4)" ::: "memory"); \
    else if ((t) == KSTEPS - 2) asm volatile("s_waitcnt vmcnt(0)" ::: "memory"); \
    if ((t) < KSTEPS - 1) __builtin_amdgcn_s_barrier(); \
}

    for (int t = 0; t < KSTEPS; t += 2) {
        GTILE(t,     bA0, bA1, bA2, bA3, bB0, bB1, bB2, bB3)
        GTILE(t + 1, bB0, bB1, bB2, bB3, bA0, bA1, bA2, bA3)
    }
#undef GTILE
#undef STAGE_A

    // epilogue: h = tanh(acc + qb), partial score over this wave's 64 n-cols
    const int bidx = m0 >> 11;   // BM=256 divides SEQ=2048
    float qv[4], vv[4];
    #pragma unroll
    for (int ni = 0; ni < 4; ni++) {
        int n_g = n0 + wn * 64 + ni * 16 + fr;
        qv[ni] = qb[bidx * HDIM + n_g];
        vv[ni] = vaw[n_g];
    }
    const int slice = bx * 4 + wn;
    float* sl = sp + ((size_t)slice * BATCH + bidx) * SEQ;
    #pragma unroll
    for (int mi = 0; mi < 8; mi++) {
        #pragma unroll
        for (int r = 0; r < 4; r++) {
            float p = 0.f;
            #pragma unroll
            for (int ni = 0; ni < 4; ni++) {
                float x = acc[mi][ni][r] + qv[ni];
                float e = __expf(2.f * x);          // tanh = 1 - 2/(e^{2x}+1), NaN-free
                p += (1.f - 2.f / (e + 1.f)) * vv[ni];
            }
            p += __shfl_xor(p, 1);
            p += __shfl_xor(p, 2);
            p += __shfl_xor(p, 4);
            p += __shfl_xor(p, 8);
            if (fr == 0) {
                int s_g = (m0 + wm * 128 + mi * 16 + fq * 4 + r) & (SEQ - 1);
                sl[s_g] = p;
            }
        }
    }
}

// ---- softmax over SEQ per batch; sums 16 slices; zeroes ctx region ----
// 512 threads, float4 loads: 4x the parallelism, 4x shorter latency chains.
__global__ __launch_bounds__(512) void softmax_kernel(const float* __restrict__ sp,
                                                      float* __restrict__ weights,
                                                      float* __restrict__ ctx) {
    __shared__ float red[8];
    const int b = blockIdx.x;
    const int tid = threadIdx.x;
    float2 z2 = {0.f, 0.f};
    ((float2*)(ctx + b * HDIM))[tid] = z2;      // zero context for atomics
    const int s = tid * 4;                      // SEQ/512 = 4 per thread
    float4 v = {0.f, 0.f, 0.f, 0.f};
    #pragma unroll
    for (int j = 0; j < NSLICE; j++) {
        float4 x = *(const float4*)(sp + ((size_t)j * BATCH + b) * SEQ + s);
        v.x += x.x; v.y += x.y; v.z += x.z; v.w += x.w;
    }
    float mx = fmaxf(fmaxf(v.x, v.y), fmaxf(v.z, v.w));
    #pragma unroll
    for (int m = 1; m < 64; m <<= 1) mx = fmaxf(mx, __shfl_xor(mx, m));
    if ((tid & 63) == 0) red[tid >> 6] = mx;
    __syncthreads();
    mx = fmaxf(fmaxf(fmaxf(red[0], red[1]), fmaxf(red[2], red[3])),
               fmaxf(fmaxf(red[4], red[5]), fmaxf(red[6], red[7])));
    v.x = __expf(v.x - mx); v.y = __expf(v.y - mx);
    v.z = __expf(v.z - mx); v.w = __expf(v.w - mx);
    float sum = v.x + v.y + v.z + v.w;
    #pragma unroll
    for (int m = 1; m < 64; m <<= 1) sum += __shfl_xor(sum, m);
    __syncthreads();
    if ((tid & 63) == 0) red[tid >> 6] = sum;
    __syncthreads();
    sum = (red[0] + red[1]) + (red[2] + red[3]) + (red[4] + red[5]) + (red[6] + red[7]);
    float inv = 1.f / sum;
    v.x *= inv; v.y *= inv; v.z *= inv; v.w *= inv;
    *(float4*)(weights + b * SEQ + s) = v;
}

// ---- context[b][h] = sum_s w[b][s] * keysb[b][s][h] (bf16 keys) ----
// 512 threads: 4-way s-split (64-deep chains, was 128), LDS pre-reduce keeps
// atomics at 2 per addr per block (16 total per addr, unchanged).
__global__ __launch_bounds__(512) void context_kernel(const u16* __restrict__ keysb,
                                                      const float* __restrict__ weights,
                                                      float* __restrict__ ctx) {
    __shared__ float wsm[256];
    __shared__ float part[2][128][9];   // pad 8->9: conflict-free column writes
    const int b = blockIdx.x;
    const int s0 = blockIdx.y * 256;
    const int tid = threadIdx.x;
    if (tid < 256) wsm[tid] = weights[b * SEQ + s0 + tid];
    __syncthreads();
    const int hq = tid & 127;
    const int sq = tid >> 7;            // 0..3
    const int sh = sq * 64;
    float a0 = 0.f, a1 = 0.f, a2 = 0.f, a3 = 0.f;
    float a4 = 0.f, a5 = 0.f, a6 = 0.f, a7 = 0.f;
    const uint4* kp = (const uint4*)(keysb + (size_t)b * SEQ * HDIM
                                     + (size_t)(s0 + sh) * HDIM) + hq;
    #pragma unroll 8
    for (int s = 0; s < 64; s++) {
        uint4 kv = kp[s * 128];            // row stride = 1024 u16 = 128 uint4
        float wv = wsm[sh + s];
        a0 += wv * __uint_as_float(kv.x << 16);
        a1 += wv * __uint_as_float(kv.x & 0xFFFF0000u);
        a2 += wv * __uint_as_float(kv.y << 16);
        a3 += wv * __uint_as_float(kv.y & 0xFFFF0000u);
        a4 += wv * __uint_as_float(kv.z << 16);
        a5 += wv * __uint_as_float(kv.z & 0xFFFF0000u);
        a6 += wv * __uint_as_float(kv.w << 16);
        a7 += wv * __uint_as_float(kv.w & 0xFFFF0000u);
    }
    if (sq >= 2) {
        float* p = part[sq - 2][hq];
        p[0] = a0; p[1] = a1; p[2] = a2; p[3] = a3;
        p[4] = a4; p[5] = a5; p[6] = a6; p[7] = a7;
    }
    __syncthreads();
    if (sq < 2) {
        const float* p = part[sq][hq];
        float* o = ctx + b * HDIM + hq * 8;
        atomicAdd(o + 0, a0 + p[0]);
        atomicAdd(o + 1, a1 + p[1]);
        atomicAdd(o + 2, a2 + p[2]);
        atomicAdd(o + 3, a3 + p[3]);
        atomicAdd(o + 4, a4 + p[4]);
        atomicAdd(o + 5, a5 + p[5]);
        atomicAdd(o + 6, a6 + p[6]);
        atomicAdd(o + 7, a7 + p[7]);
    }
}

extern "C" void kernel_launch(void* const* d_in, const int* in_sizes, int n_in,
                              void* d_out, int out_size, void* d_ws, size_t ws_size,
                              hipStream_t stream) {
    const float* query = (const float*)d_in[0];
    const float* keys  = (const float*)d_in[1];
    const float* Wa_w  = (const float*)d_in[2];
    const float* Wa_b  = (const float*)d_in[3];
    const float* Ua_w  = (const float*)d_in[4];
    const float* Ua_b  = (const float*)d_in[5];
    const float* Va_w  = (const float*)d_in[6];
    // Va_b unused: softmax is shift-invariant.
    float* out = (float*)d_out;   // [0, 32768) context, [32768, 98304) weights

    char* ws = (char*)d_ws;
    u16*  keysb = (u16*)ws;                                     // 134217728 B
    u16*  uab   = (u16*)(ws + 134217728);                       //   2097152 B
    float* qb   = (float*)(ws + 134217728 + 2097152);           //    131072 B
    float* sp   = (float*)(ws + 134217728 + 2097152 + 131072);  //   4194304 B (16 slices)

    cvt_kernel<<<2048, 256, 0, stream>>>(keys, keysb, BATCH * SEQ * HDIM / 8);
    cvt_kernel<<<512, 256, 0, stream>>>(Ua_w, uab, HDIM * HDIM / 8);
    qb_kernel<<<dim3(BATCH, HDIM / 64), 256, 0, stream>>>(query, Wa_w, Wa_b, Ua_b, qb);
    gemm_score_kernel<<<dim3(HDIM / BN, M_TOTAL / BM), 512, 0, stream>>>(keysb, uab, qb, Va_w, sp);
    softmax_kernel<<<BATCH, 512, 0, stream>>>(sp, out + BATCH * HDIM, out);
    context_kernel<<<dim3(BATCH, 8), 512, 0, stream>>>(keysb, out + BATCH * HDIM, out);
}

// Round 7
// 609.116 us; speedup vs baseline: 1.1297x; 1.1297x over previous
//
#include <hip/hip_runtime.h>
#include <hip/hip_bf16.h>

#define HDIM 1024
#define SEQ  2048
#define BATCH 32
#define M_TOTAL (BATCH * SEQ)   // 65536
#define BM 256
#define BN 256
#define BK 64
#define KSTEPS (HDIM / BK)      // 16
#define NSLICE 16               // 4 n-blocks x 4 n-waves

typedef __bf16 bf16x8 __attribute__((ext_vector_type(8)));
typedef float  f32x4  __attribute__((ext_vector_type(4)));
typedef unsigned short u16;
#define AS1 __attribute__((address_space(1)))
#define AS3 __attribute__((address_space(3)))

__device__ __forceinline__ u16 f2bf(float f) {
    unsigned int u = __float_as_uint(f);
    u += 0x7FFFu + ((u >> 16) & 1u);   // round-to-nearest-even
    return (u16)(u >> 16);
}

// ---- fp32 -> bf16, 8 elems/thread, grid-stride ----
__global__ __launch_bounds__(256) void cvt_kernel(const float* __restrict__ in,
                                                  u16* __restrict__ out, int n8) {
    const int stride = gridDim.x * 256;
    for (int idx = blockIdx.x * 256 + threadIdx.x; idx < n8; idx += stride) {
        size_t i = (size_t)idx * 8;
        float4 f0 = *(const float4*)(in + i);
        float4 f1 = *(const float4*)(in + i + 4);
        uint4 v;
        v.x = (unsigned)f2bf(f0.x) | ((unsigned)f2bf(f0.y) << 16);
        v.y = (unsigned)f2bf(f0.z) | ((unsigned)f2bf(f0.w) << 16);
        v.z = (unsigned)f2bf(f1.x) | ((unsigned)f2bf(f1.y) << 16);
        v.w = (unsigned)f2bf(f1.z) | ((unsigned)f2bf(f1.w) << 16);
        *(uint4*)(out + i) = v;
    }
}

// ---- qb[b][o] = query[b]·Wa_w[o] + Wa_b[o] + Ua_b[o] (fp32) ----
__global__ __launch_bounds__(256) void qb_kernel(const float* __restrict__ query,
                                                 const float* __restrict__ Wa_w,
                                                 const float* __restrict__ Wa_b,
                                                 const float* __restrict__ Ua_b,
                                                 float* __restrict__ qb) {
    __shared__ float qs[HDIM];
    const int b = blockIdx.x;
    const int tid = threadIdx.x;
    ((float4*)qs)[tid] = ((const float4*)(query + b * HDIM))[tid];
    __syncthreads();
    const int lane = tid & 63;
    const int w = tid >> 6;
    const int obase = blockIdx.y * 64 + w * 16;
    for (int i = 0; i < 16; i++) {
        int o = obase + i;
        const float4* wrow = (const float4*)(Wa_w + (size_t)o * HDIM);
        float s = 0.f;
        #pragma unroll
        for (int j = 0; j < 4; j++) {
            float4 wv = wrow[j * 64 + lane];
            float4 qv = ((const float4*)qs)[j * 64 + lane];
            s += wv.x * qv.x + wv.y * qv.y + wv.z * qv.z + wv.w * qv.w;
        }
        #pragma unroll
        for (int m = 1; m < 64; m <<= 1) s += __shfl_xor(s, m);
        if (lane == 0) qb[b * HDIM + o] = s + Wa_b[o] + Ua_b[o];
    }
}

// raw ds_read_b128 (invisible to LDS-DMA alias waitcnt logic); lgkm waits are
// manual COUNTED waits (rule #18: wait + sched_barrier(0) before MFMA).
#define DSREAD(dst, base, imm) \
    asm volatile("ds_read_b128 %0, %1 offset:" #imm : "=v"(dst) : "v"(base))

#define MFMA4(mi, av, c0, c1, c2, c3) \
    acc[mi][0] = __builtin_amdgcn_mfma_f32_16x16x32_bf16(av, c0, acc[mi][0], 0, 0, 0); \
    acc[mi][1] = __builtin_amdgcn_mfma_f32_16x16x32_bf16(av, c1, acc[mi][1], 0, 0, 0); \
    acc[mi][2] = __builtin_amdgcn_mfma_f32_16x16x32_bf16(av, c2, acc[mi][2], 0, 0, 0); \
    acc[mi][3] = __builtin_amdgcn_mfma_f32_16x16x32_bf16(av, c3, acc[mi][3], 0, 0, 0);

// ---- GEMM keysb·Ua^T + fused tanh + Va dot -> deterministic score slices ----
// BK=64: halves barriers/waits/gates per K-element vs round-4's BK=32 while
// keeping its proven counted-lgkm in-tile pipeline. K-64 tile stored as TWO
// BK=32 sub-tiles, each byte-identical to round-4's zero-conflict layout.
// 2-slot ring (128 KiB). 4 phases x 16 MFMA per tile; cross-tile prefetch
// after a mid-tile vmcnt(0)+barrier (stages issued >=1200 cyc earlier).
__global__ __launch_bounds__(512, 2) void gemm_score_kernel(const u16* __restrict__ keysb,
                                                            const u16* __restrict__ uab,
                                                            const float* __restrict__ qb,
                                                            const float* __restrict__ vaw,
                                                            float* __restrict__ sp) {
    __shared__ __align__(16) u16 As[2][2][BM * 32];   // [slot][kh] 16 KB each = 64 KB
    __shared__ __align__(16) u16 Bs[2][2][BN * 32];   // 64 KB

    const int tid  = threadIdx.x;
    const int lane = tid & 63;
    const int w    = tid >> 6;          // 0..7
    const int wm   = w >> 2;            // 0..1  -> rows [wm*128, +128)
    const int wn   = w & 3;             // 0..3  -> cols [wn*64, +64)

    // XCD-chunked swizzle: 128 consecutive remapped blocks per XCD, n-fastest
    const int bid = blockIdx.y * 4 + blockIdx.x;         // dispatch order
    const int swz = (bid & 7) * 128 + (bid >> 3);        // bijective (1024 % 8 == 0)
    const int bx  = swz & 3;
    const int by  = swz >> 2;
    const int n0  = bx * BN;
    const int m0  = by * BM;

    // ---- staging (linear LDS dest, pre-swizzled global source), per kh ----
    // sub-tile row = 32 k = 64 B = 4 x 16B slots; LDS(r,s) = global s^((r>>1)&3)
    const int srow = lane >> 2;                          // 16 rows per issue
    const int cs   = (lane & 3) ^ ((lane >> 3) & 3);     // swizzled source slot
    const u16* gA0 = keysb + (size_t)(m0 + w * 32 + srow) * HDIM + cs * 8;
    const u16* gB0 = uab   + (size_t)(n0 + w * 32 + srow) * HDIM + cs * 8;

    // ---- fragment read addressing (round-4 swizzle), byte offsets ----
    const int fr = lane & 15;
    const int fq = lane >> 4;
    const int sA = fq ^ ((fr >> 1) & 3);                 // row-bit-independent
    const unsigned aB0 = (unsigned)(unsigned long long)(const AS3 u16*)&As[0][0][0]
                       + (unsigned)(((wm * 128 + fr) * 32 + sA * 8) * 2);
    const unsigned bB0 = (unsigned)(unsigned long long)(const AS3 u16*)&Bs[0][0][0]
                       + (unsigned)(((wn * 64  + fr) * 32 + sA * 8) * 2);

    f32x4 acc[8][4] = {};

#define STAGE_A(kt, kh) { \
    u16* d = &As[(kt) & 1][kh][w * 32 * 32]; \
    const u16* s = gA0 + (size_t)(kt) * 64 + (kh) * 32; \
    __builtin_amdgcn_global_load_lds((AS1 void*)s, (AS3 void*)d, 16, 0, 0); \
    __builtin_amdgcn_global_load_lds((AS1 void*)(s + 16 * HDIM), (AS3 void*)(d + 16 * 32), 16, 0, 0); }
#define STAGE_B(kt, kh) { \
    u16* d = &Bs[(kt) & 1][kh][w * 32 * 32]; \
    const u16* s = gB0 + (size_t)(kt) * 64 + (kh) * 32; \
    __builtin_amdgcn_global_load_lds((AS1 void*)s, (AS3 void*)d, 16, 0, 0); \
    __builtin_amdgcn_global_load_lds((AS1 void*)(s + 16 * HDIM), (AS3 void*)(d + 16 * 32), 16, 0, 0); }

    bf16x8 a0, a1, a2, a3, a4, a5, a6, a7;   // kh0 then reused for kh1
    bf16x8 b0, b1, b2, b3;                   // B kh0
    bf16x8 c0, c1, c2, c3;                   // B kh1

    // prologue: stage slot 0 (8 issues), drain, sync, prefetch R0(slot0,kh0)
    STAGE_A(0, 0) STAGE_A(0, 1) STAGE_B(0, 0) STAGE_B(0, 1)
    asm volatile("s_waitcnt vmcnt(0)" ::: "memory");
    __builtin_amdgcn_s_barrier();
    DSREAD(a0, aB0, 0);    DSREAD(a1, aB0, 1024);
    DSREAD(a2, aB0, 2048); DSREAD(a3, aB0, 3072);
    DSREAD(b0, bB0, 0);    DSREAD(b1, bB0, 1024);
    DSREAD(b2, bB0, 2048); DSREAD(b3, bB0, 3072);

    for (int t = 0; t < KSTEPS; ++t) {
        // TOP barrier: readers of slot (t+1)&1 (= tile t-1) all done
        __builtin_amdgcn_s_barrier();
        const unsigned at = aB0 + ((t & 1) << 15);   // slot stride 32 KiB
        const unsigned bt = bB0 + ((t & 1) << 15);

        // stage A(t+1) both kh; R1: a4-7 kh0
        if (t + 1 < KSTEPS) { STAGE_A(t + 1, 0) STAGE_A(t + 1, 1) }
        DSREAD(a4, at, 4096); DSREAD(a5, at, 5120);
        DSREAD(a6, at, 6144); DSREAD(a7, at, 7168);
        asm volatile("s_waitcnt lgkmcnt(4)" ::: "memory");   // R0 retired
        __builtin_amdgcn_sched_barrier(0);
        __builtin_amdgcn_s_setprio(1);
        MFMA4(0, a0, b0, b1, b2, b3)
        MFMA4(1, a1, b0, b1, b2, b3)
        MFMA4(2, a2, b0, b1, b2, b3)
        MFMA4(3, a3, b0, b1, b2, b3)
        __builtin_amdgcn_s_setprio(0);

        // R2: a0-3 kh1 + c0-3 kh1; stage B(t+1) both kh
        DSREAD(a0, at, 16384); DSREAD(a1, at, 17408);
        DSREAD(a2, at, 18432); DSREAD(a3, at, 19456);
        DSREAD(c0, bt, 16384); DSREAD(c1, bt, 17408);
        DSREAD(c2, bt, 18432); DSREAD(c3, bt, 19456);
        if (t + 1 < KSTEPS) { STAGE_B(t + 1, 0) STAGE_B(t + 1, 1) }
        asm volatile("s_waitcnt lgkmcnt(8)" ::: "memory");   // R1 retired
        __builtin_amdgcn_sched_barrier(0);
        __builtin_amdgcn_s_setprio(1);
        MFMA4(4, a4, b0, b1, b2, b3)
        MFMA4(5, a5, b0, b1, b2, b3)
        MFMA4(6, a6, b0, b1, b2, b3)
        MFMA4(7, a7, b0, b1, b2, b3)
        __builtin_amdgcn_s_setprio(0);

        // R3: a4-7 kh1
        DSREAD(a4, at, 20480); DSREAD(a5, at, 21504);
        DSREAD(a6, at, 22528); DSREAD(a7, at, 23552);
        asm volatile("s_waitcnt lgkmcnt(4)" ::: "memory");   // R2 retired
        __builtin_amdgcn_sched_barrier(0);
        __builtin_amdgcn_s_setprio(1);
        MFMA4(0, a0, c0, c1, c2, c3)
        MFMA4(1, a1, c0, c1, c2, c3)
        MFMA4(2, a2, c0, c1, c2, c3)
        MFMA4(3, a3, c0, c1, c2, c3)
        __builtin_amdgcn_s_setprio(0);

        // MID: own stage(t+1) drained; barrier -> all waves' stage(t+1) done
        asm volatile("s_waitcnt vmcnt(0)" ::: "memory");
        __builtin_amdgcn_s_barrier();
        if (t + 1 < KSTEPS) {
            // prefetch R0'(slot t+1, kh0)
            const unsigned an = aB0 + (((t + 1) & 1) << 15);
            const unsigned bn = bB0 + (((t + 1) & 1) << 15);
            DSREAD(a0, an, 0);    DSREAD(a1, an, 1024);
            DSREAD(a2, an, 2048); DSREAD(a3, an, 3072);
            DSREAD(b0, bn, 0);    DSREAD(b1, bn, 1024);
            DSREAD(b2, bn, 2048); DSREAD(b3, bn, 3072);
            asm volatile("s_waitcnt lgkmcnt(8)" ::: "memory");   // R3 retired
        } else {
            asm volatile("s_waitcnt lgkmcnt(0)" ::: "memory");
        }
        __builtin_amdgcn_sched_barrier(0);
        __builtin_amdgcn_s_setprio(1);
        MFMA4(4, a4, c0, c1, c2, c3)
        MFMA4(5, a5, c0, c1, c2, c3)
        MFMA4(6, a6, c0, c1, c2, c3)
        MFMA4(7, a7, c0, c1, c2, c3)
        __builtin_amdgcn_s_setprio(0);
    }
#undef STAGE_A
#undef STAGE_B

    // epilogue: h = tanh(acc + qb), partial score over this wave's 64 n-cols
    const int bidx = m0 >> 11;   // BM=256 divides SEQ=2048
    float qv[4], vv[4];
    #pragma unroll
    for (int ni = 0; ni < 4; ni++) {
        int n_g = n0 + wn * 64 + ni * 16 + fr;
        qv[ni] = qb[bidx * HDIM + n_g];
        vv[ni] = vaw[n_g];
    }
    const int slice = bx * 4 + wn;
    float* sl = sp + ((size_t)slice * BATCH + bidx) * SEQ;
    #pragma unroll
    for (int mi = 0; mi < 8; mi++) {
        #pragma unroll
        for (int r = 0; r < 4; r++) {
            float p = 0.f;
            #pragma unroll
            for (int ni = 0; ni < 4; ni++) {
                float x = acc[mi][ni][r] + qv[ni];
                float e = __expf(2.f * x);          // tanh = 1 - 2/(e^{2x}+1), NaN-free
                p += (1.f - 2.f / (e + 1.f)) * vv[ni];
            }
            p += __shfl_xor(p, 1);
            p += __shfl_xor(p, 2);
            p += __shfl_xor(p, 4);
            p += __shfl_xor(p, 8);
            if (fr == 0) {
                int s_g = (m0 + wm * 128 + mi * 16 + fq * 4 + r) & (SEQ - 1);
                sl[s_g] = p;
            }
        }
    }
}

// ---- softmax over SEQ per batch; sums 16 slices; zeroes ctx region ----
__global__ __launch_bounds__(512) void softmax_kernel(const float* __restrict__ sp,
                                                      float* __restrict__ weights,
                                                      float* __restrict__ ctx) {
    __shared__ float red[8];
    const int b = blockIdx.x;
    const int tid = threadIdx.x;
    float2 z2 = {0.f, 0.f};
    ((float2*)(ctx + b * HDIM))[tid] = z2;      // zero context for atomics
    const int s = tid * 4;                      // SEQ/512 = 4 per thread
    float4 v = {0.f, 0.f, 0.f, 0.f};
    #pragma unroll
    for (int j = 0; j < NSLICE; j++) {
        float4 x = *(const float4*)(sp + ((size_t)j * BATCH + b) * SEQ + s);
        v.x += x.x; v.y += x.y; v.z += x.z; v.w += x.w;
    }
    float mx = fmaxf(fmaxf(v.x, v.y), fmaxf(v.z, v.w));
    #pragma unroll
    for (int m = 1; m < 64; m <<= 1) mx = fmaxf(mx, __shfl_xor(mx, m));
    if ((tid & 63) == 0) red[tid >> 6] = mx;
    __syncthreads();
    mx = fmaxf(fmaxf(fmaxf(red[0], red[1]), fmaxf(red[2], red[3])),
               fmaxf(fmaxf(red[4], red[5]), fmaxf(red[6], red[7])));
    v.x = __expf(v.x - mx); v.y = __expf(v.y - mx);
    v.z = __expf(v.z - mx); v.w = __expf(v.w - mx);
    float sum = v.x + v.y + v.z + v.w;
    #pragma unroll
    for (int m = 1; m < 64; m <<= 1) sum += __shfl_xor(sum, m);
    __syncthreads();
    if ((tid & 63) == 0) red[tid >> 6] = sum;
    __syncthreads();
    sum = (red[0] + red[1]) + (red[2] + red[3]) + (red[4] + red[5]) + (red[6] + red[7]);
    float inv = 1.f / sum;
    v.x *= inv; v.y *= inv; v.z *= inv; v.w *= inv;
    *(float4*)(weights + b * SEQ + s) = v;
}

// ---- context[b][h] = sum_s w[b][s] * keysb[b][s][h] (bf16 keys) ----
__global__ __launch_bounds__(512) void context_kernel(const u16* __restrict__ keysb,
                                                      const float* __restrict__ weights,
                                                      float* __restrict__ ctx) {
    __shared__ float wsm[256];
    __shared__ float part[2][128][9];   // pad 8->9: conflict-free column writes
    const int b = blockIdx.x;
    const int s0 = blockIdx.y * 256;
    const int tid = threadIdx.x;
    if (tid < 256) wsm[tid] = weights[b * SEQ + s0 + tid];
    __syncthreads();
    const int hq = tid & 127;
    const int sq = tid >> 7;            // 0..3
    const int sh = sq * 64;
    float a0 = 0.f, a1 = 0.f, a2 = 0.f, a3 = 0.f;
    float a4 = 0.f, a5 = 0.f, a6 = 0.f, a7 = 0.f;
    const uint4* kp = (const uint4*)(keysb + (size_t)b * SEQ * HDIM
                                     + (size_t)(s0 + sh) * HDIM) + hq;
    #pragma unroll 8
    for (int s = 0; s < 64; s++) {
        uint4 kv = kp[s * 128];            // row stride = 1024 u16 = 128 uint4
        float wv = wsm[sh + s];
        a0 += wv * __uint_as_float(kv.x << 16);
        a1 += wv * __uint_as_float(kv.x & 0xFFFF0000u);
        a2 += wv * __uint_as_float(kv.y << 16);
        a3 += wv * __uint_as_float(kv.y & 0xFFFF0000u);
        a4 += wv * __uint_as_float(kv.z << 16);
        a5 += wv * __uint_as_float(kv.z & 0xFFFF0000u);
        a6 += wv * __uint_as_float(kv.w << 16);
        a7 += wv * __uint_as_float(kv.w & 0xFFFF0000u);
    }
    if (sq >= 2) {
        float* p = part[sq - 2][hq];
        p[0] = a0; p[1] = a1; p[2] = a2; p[3] = a3;
        p[4] = a4; p[5] = a5; p[6] = a6; p[7] = a7;
    }
    __syncthreads();
    if (sq < 2) {
        const float* p = part[sq][hq];
        float* o = ctx + b * HDIM + hq * 8;
        atomicAdd(o + 0, a0 + p[0]);
        atomicAdd(o + 1, a1 + p[1]);
        atomicAdd(o + 2, a2 + p[2]);
        atomicAdd(o + 3, a3 + p[3]);
        atomicAdd(o + 4, a4 + p[4]);
        atomicAdd(o + 5, a5 + p[5]);
        atomicAdd(o + 6, a6 + p[6]);
        atomicAdd(o + 7, a7 + p[7]);
    }
}

extern "C" void kernel_launch(void* const* d_in, const int* in_sizes, int n_in,
                              void* d_out, int out_size, void* d_ws, size_t ws_size,
                              hipStream_t stream) {
    const float* query = (const float*)d_in[0];
    const float* keys  = (const float*)d_in[1];
    const float* Wa_w  = (const float*)d_in[2];
    const float* Wa_b  = (const float*)d_in[3];
    const float* Ua_w  = (const float*)d_in[4];
    const float* Ua_b  = (const float*)d_in[5];
    const float* Va_w  = (const float*)d_in[6];
    // Va_b unused: softmax is shift-invariant.
    float* out = (float*)d_out;   // [0, 32768) context, [32768, 98304) weights

    char* ws = (char*)d_ws;
    u16*  keysb = (u16*)ws;                                     // 134217728 B
    u16*  uab   = (u16*)(ws + 134217728);                       //   2097152 B
    float* qb   = (float*)(ws + 134217728 + 2097152);           //    131072 B
    float* sp   = (float*)(ws + 134217728 + 2097152 + 131072);  //   4194304 B (16 slices)

    cvt_kernel<<<2048, 256, 0, stream>>>(keys, keysb, BATCH * SEQ * HDIM / 8);
    cvt_kernel<<<512, 256, 0, stream>>>(Ua_w, uab, HDIM * HDIM / 8);
    qb_kernel<<<dim3(BATCH, HDIM / 64), 256, 0, stream>>>(query, Wa_w, Wa_b, Ua_b, qb);
    gemm_score_kernel<<<dim3(HDIM / BN, M_TOTAL / BM), 512, 0, stream>>>(keysb, uab, qb, Va_w, sp);
    softmax_kernel<<<BATCH, 512, 0, stream>>>(sp, out + BATCH * HDIM, out);
    context_kernel<<<dim3(BATCH, 8), 512, 0, stream>>>(keysb, out + BATCH * HDIM, out);
}